// Round 1
// baseline (11276.273 us; speedup 1.0000x reference)
//
#include <hip/hip_runtime.h>
#include <math.h>

typedef unsigned short u16;
typedef unsigned int   u32;
typedef unsigned long long u64;
typedef __attribute__((ext_vector_type(8))) short short8;
typedef __attribute__((ext_vector_type(4))) float f32x4;
typedef __attribute__((ext_vector_type(4))) unsigned int u32x4;

__device__ __forceinline__ u16 f2bf(float f) {
    u32 u = __float_as_uint(f);
    u32 r = (u + 0x7fffu + ((u >> 16) & 1u)) >> 16;
    return (u16)r;
}
__device__ __forceinline__ u32 pk2(float a, float b) {
    return ((u32)f2bf(a)) | (((u32)f2bf(b)) << 16);
}
__device__ __forceinline__ float sigm(float x) { return 1.f / (1.f + __expf(-x)); }
__device__ __forceinline__ f32x4 mfma16(short8 a, short8 b, f32x4 c) {
    return __builtin_amdgcn_mfma_f32_16x16x32_bf16(a, b, c, 0, 0, 0);
}
__device__ __forceinline__ short8 ld8bf(const float* p) {
    short8 r;
#pragma unroll
    for (int j = 0; j < 8; ++j) r[j] = (short)f2bf(p[j]);
    return r;
}
// 16B cache-bypassing load straight from the coherence point.
__device__ __forceinline__ u32x4 ldg16cv4(const u16* p) {
    u32x4 r;
    asm volatile("global_load_dwordx4 %0, %1, off sc0 sc1" : "=v"(r) : "v"(p));
    return r;
}
__device__ __forceinline__ void waitvm() {
    asm volatile("s_waitcnt vmcnt(0)" ::: "memory");
}
// NOT-decode a published chunk into LDS (16B aligned).
__device__ __forceinline__ void st_not16(u16* dst, u32x4 w) {
    u32x4 d; d[0] = ~w[0]; d[1] = ~w[1]; d[2] = ~w[2]; d[3] = ~w[3];
    *(u32x4*)dst = d;
}
__device__ __forceinline__ void st_zero16(u16* dst) {
    u32x4 d = {0u, 0u, 0u, 0u};
    *(u32x4*)dst = d;
}

#define FLAG_STRIDE 16   /* ints -> 64B per flag slot */
#define XL_OFF 16384000
#define PS_OFF 16384016

// ws layout (bytes)
#define WS_FLAGS   0        /* 512 slots x 64B = 32768 (progress counters only) */
#define WS_HBUF_F  32768    /* 3 layers x 16 slots x 16KB = 786432 -> end 819200 */
#define WS_HBUF_W  819200   /* 16 slots x 8KB = 131072 -> end 950272 */
#define WS_REPS    950272   /* 1600x512 fp32 = 3276800 -> end 4227072 */
#define WS_RW      4227072  /* 1600x256 bf16 = 819200 -> end 5046272 */
#define WS_HSEQ    5046272  /* 1600x256 fp32 = 1638400 -> end 6684672 */
#define WS_FPWB    6684672  /* 512x512 bf16 = 524288 -> end 7208960 */

// ---------------------------------------------------------------------------
// Persistent 3-layer frame LSTM. 192 WGs (64 per layer), 128 threads each.
// h exchange is SELF-VALIDATING: producers publish ~pk (bitwise NOT of the
// bf16 pair); 0 means "not written" (pk==0xFFFFFFFF would need bf16 -NaN,
// impossible for |h|<1). Consumers poll the data chunks directly -> ONE
// coherence-point round trip per step instead of three (no store-ack wait,
// no flag hop). Ring-16; producers re-zero slot (t+8)&15 at step t, gated by
// a lazily-checked next-layer progress counter (fn >= t-6).
// ---------------------------------------------------------------------------
template<int KTIN, bool L0, bool HASNEXT>
__device__ __forceinline__ void frame_body(
    const int layer, const int kwg,
    const float* __restrict__ Wih, const float* __restrict__ Whh, const float* __restrict__ bias,
    const float* __restrict__ x, u16* __restrict__ hbuf, int* __restrict__ flags,
    float* __restrict__ h3out, float* sC, u16* sxpad, u16* AsIn, u16* AsOwn)
{
    const int tid  = threadIdx.x;
    const int lane = tid & 63;
    const int wave = tid >> 6;
    const int n16  = lane & 15;
    const int quad = lane >> 4;
    const int koff = quad * 8;

    if (L0) {                                            // zero the x pad cols [80,96)
        for (int e = tid; e < 256; e += 128) sxpad[(e >> 4) * 96 + 80 + (e & 15)] = 0;
    }

    // B fragments in registers. wave0 -> tile (i|f), wave1 -> tile (g|o).
    const int grow = wave * 1024 + ((n16 >> 3) * 512) + kwg * 8 + (n16 & 7);
    short8 bfr[KTIN + 16];
#pragma unroll
    for (int kt = 0; kt < KTIN; ++kt) {
        short8 v = {0,0,0,0,0,0,0,0};
        const int k = kt * 32 + koff;
        if (L0) { if (k + 8 <= 80) v = ld8bf(Wih + grow * 80 + k); }
        else    { v = ld8bf(Wih + (size_t)grow * 512 + k); }
        bfr[kt] = v;
    }
#pragma unroll
    for (int kt = 0; kt < 16; ++kt)
        bfr[KTIN + kt] = ld8bf(Whh + (size_t)grow * 512 + kt * 32 + koff);

    // gate phase: one (batch, col) value per lane; c-state lives in a register
    const int gb = tid & 15;
    const int gj = tid >> 4;
    const int gc = kwg * 8 + gj;
    const float bI = bias[gc], bF = bias[512 + gc], bG = bias[1024 + gc], bO = bias[1536 + gc];
    float creg = 0.f;

    int* myflag   = flags + (layer * 64 + kwg) * FLAG_STRIDE;
    const int* fN = flags + ((layer + 1) * 64) * FLAG_STRIDE;
    int fnc = 0;                                     // cached next-layer progress (wave0)
    u16* lbase = hbuf + (size_t)layer * 16 * 8192;
    const u16* pbase = hbuf + (size_t)(layer > 0 ? layer - 1 : 0) * 16 * 8192;
    __syncthreads();

    for (int t = 0; t < 2000; ++t) {
        // ---- wave0: lazily gate + re-arm slot (t+8)&15 with zeros ----
        if (wave == 0) {
            if (HASNEXT && !__all(fnc >= t - 6)) {
                int guard = 0;
                do {
                    fnc = __hip_atomic_load(fN + lane * FLAG_STRIDE, __ATOMIC_RELAXED, __HIP_MEMORY_SCOPE_AGENT);
                    __builtin_amdgcn_s_sleep(1);
                } while (!__all(fnc >= t - 6) && ++guard < (1 << 22));
            }
            u32* z = (u32*)(lbase + ((size_t)((t + 8) & 15)) * 8192)
                   + (lane & 15) * 256 + kwg * 4 + (lane >> 4);
            __hip_atomic_store(z, 0u, __ATOMIC_RELAXED, __HIP_MEMORY_SCOPE_AGENT);
        }

        // ---- issue x loads early (L0) so they fly under the poll ----
        float4 xv0, xv1, xv2;
        const int e0 = tid, e1 = tid + 128, e2 = tid + 256;
        if (L0) {
            xv0 = *(const float4*)(x + ((size_t)(e0 / 20) * 2000 + t) * 80 + (e0 % 20) * 4);
            xv1 = *(const float4*)(x + ((size_t)(e1 / 20) * 2000 + t) * 80 + (e1 % 20) * 4);
            if (e2 < 320)
                xv2 = *(const float4*)(x + ((size_t)(e2 / 20) * 2000 + t) * 80 + (e2 % 20) * 4);
        }

        // ---- data-poll: chunks [0..7]=hin (prev layer h_t), [8..15]=own h_{t-1} ----
        u32x4 v[16];
        const u16* hin  = pbase + ((size_t)(t & 15)) * 8192;
        const u16* hown = lbase + ((size_t)((t - 1) & 15)) * 8192;
        u32 pend = (L0 ? 0u : 0x00FFu) | (t > 0 ? 0xFF00u : 0u);
        int guard = 0;
        while (pend) {
#pragma unroll
            for (int i = 0; i < 8; ++i)
                if (!L0 && (pend & (1u << i)))   v[i]     = ldg16cv4(hin  + (tid + 128 * i) * 8);
#pragma unroll
            for (int i = 0; i < 8; ++i)
                if (pend & (0x100u << i))        v[8 + i] = ldg16cv4(hown + (tid + 128 * i) * 8);
            waitvm();
#pragma unroll
            for (int i = 0; i < 16; ++i)
                if ((pend & (1u << i)) && v[i][0] && v[i][1] && v[i][2] && v[i][3])
                    pend &= ~(1u << i);
            if (++guard > (1 << 20)) break;      // anti-hang escape
        }

        // ---- stage into LDS (NOT-decode) ----
        if (L0) {
            u32* d0 = (u32*)(sxpad + (e0 / 20) * 96 + (e0 % 20) * 4);
            d0[0] = pk2(xv0.x, xv0.y); d0[1] = pk2(xv0.z, xv0.w);
            u32* d1 = (u32*)(sxpad + (e1 / 20) * 96 + (e1 % 20) * 4);
            d1[0] = pk2(xv1.x, xv1.y); d1[1] = pk2(xv1.z, xv1.w);
            if (e2 < 320) {
                u32* d2 = (u32*)(sxpad + (e2 / 20) * 96 + (e2 % 20) * 4);
                d2[0] = pk2(xv2.x, xv2.y); d2[1] = pk2(xv2.z, xv2.w);
            }
        }
#pragma unroll
        for (int i = 0; i < 8; ++i) {
            const int c = tid + 128 * i;
            const int row = c >> 6, col8 = (c & 63) << 3;
            if (!L0) st_not16(AsIn + row * 520 + col8, v[i]);
            if (t > 0) st_not16(AsOwn + row * 520 + col8, v[8 + i]);
            else       st_zero16(AsOwn + row * 520 + col8);
        }
        __syncthreads();

        // ---- gate GEMM ----
        f32x4 acc[4] = {{0,0,0,0},{0,0,0,0},{0,0,0,0},{0,0,0,0}};
#pragma unroll
        for (int kt = 0; kt < KTIN; ++kt) {
            short8 a;
            if (L0) a = *(const short8*)(sxpad + n16 * 96 + kt * 32 + koff);
            else    a = *(const short8*)(AsIn + n16 * 520 + kt * 32 + koff);
            acc[kt & 3] = mfma16(a, bfr[kt], acc[kt & 3]);
        }
#pragma unroll
        for (int kt = 0; kt < 16; ++kt) {
            short8 a = *(const short8*)(AsOwn + n16 * 520 + kt * 32 + koff);
            acc[(KTIN + kt) & 3] = mfma16(a, bfr[KTIN + kt], acc[(KTIN + kt) & 3]);
        }
        const f32x4 C = acc[0] + acc[1] + acc[2] + acc[3];
#pragma unroll
        for (int r = 0; r < 4; ++r)
            sC[(wave * 16 + quad * 4 + r) * 17 + n16] = C[r];   // [wave*16+batch][gate]
        __syncthreads();

        // ---- gate math on all 128 lanes + self-validating publish ----
        const float gi = sC[gb * 17 + gj]            + bI;
        const float gf = sC[gb * 17 + 8 + gj]        + bF;
        const float gg = sC[(16 + gb) * 17 + gj]     + bG;
        const float go = sC[(16 + gb) * 17 + 8 + gj] + bO;
        const float cn = sigm(gf) * creg + sigm(gi) * tanhf(gg);
        const float hn = sigm(go) * tanhf(cn);
        creg = cn;
        if (!HASNEXT)  // layer 2
            h3out[((size_t)(gb * 2000 + t)) * 512 + gc] = hn;
        const u32 mb = (u32)f2bf(hn);
        const u32 nb = (u32)__shfl_xor((int)mb, 16, 64);
        if (!(gj & 1)) {
            const u32 enc = ~(mb | (nb << 16));      // NOT-encoded: 0 == "not written"
            u32* hd = (u32*)(lbase + ((size_t)(t & 15)) * 8192)
                    + gb * 256 + kwg * 4 + (gj >> 1);
            __hip_atomic_store(hd, enc, __ATOMIC_RELAXED, __HIP_MEMORY_SCOPE_AGENT);
        }
        if (tid == 0)   // progress counter (gates upstream zeroing only)
            __hip_atomic_store(myflag, t + 1, __ATOMIC_RELAXED, __HIP_MEMORY_SCOPE_AGENT);
    }
}

__global__ __launch_bounds__(128, 1) void k_frame_lstm(
    const float* __restrict__ x,
    const float* __restrict__ Wih0, const float* __restrict__ Whh0, const float* __restrict__ b0,
    const float* __restrict__ Wih1, const float* __restrict__ Whh1, const float* __restrict__ b1,
    const float* __restrict__ Wih2, const float* __restrict__ Whh2, const float* __restrict__ b2,
    u16* hbuf, int* flags, float* h3out)
{
    __shared__ __align__(16) u16 sxpad[16 * 96];
    __shared__ __align__(16) u16 AsIn[16 * 520];
    __shared__ __align__(16) u16 AsOwn[16 * 520];
    __shared__ float sC[32 * 17];
    const int wgid = blockIdx.x;
    const int layer = wgid >> 6;
    const int kwg = wgid & 63;
    if (layer == 0)      frame_body<3,  true,  true >(0, kwg, Wih0, Whh0, b0, x, hbuf, flags, h3out, sC, sxpad, AsIn, AsOwn);
    else if (layer == 1) frame_body<16, false, true >(1, kwg, Wih1, Whh1, b1, x, hbuf, flags, h3out, sC, sxpad, AsIn, AsOwn);
    else                 frame_body<16, false, false>(2, kwg, Wih2, Whh2, b2, x, hbuf, flags, h3out, sC, sxpad, AsIn, AsOwn);
}

// ---------------------------------------------------------------------------
// Persistent word LSTM: 32 WGs x 128 threads, 100 steps, H=256.
// Same self-validating data-poll; own-h chunks feed MFMA straight from regs.
// ---------------------------------------------------------------------------
__global__ __launch_bounds__(128, 1) void k_word_lstm(
    const u16* __restrict__ rW, const float* __restrict__ Wih,
    const float* __restrict__ Whh, const float* __restrict__ bias,
    u16* __restrict__ hbufw, float* __restrict__ hseq)
{
    __shared__ float sC[32 * 17];
    const int tid = threadIdx.x;
    const int lane = tid & 63;
    const int wave = tid >> 6;
    const int n16 = lane & 15;
    const int quad = lane >> 4;
    const int koff = quad * 8;
    const int kwg = blockIdx.x;  // 0..31

    const int grow = wave * 512 + ((n16 >> 3) * 256) + kwg * 8 + (n16 & 7);
    short8 bfr[16];
#pragma unroll
    for (int kt = 0; kt < 8; ++kt) bfr[kt]     = ld8bf(Wih + (size_t)grow * 256 + kt * 32 + koff);
#pragma unroll
    for (int kt = 0; kt < 8; ++kt) bfr[8 + kt] = ld8bf(Whh + (size_t)grow * 256 + kt * 32 + koff);
    const int gb = tid & 15;
    const int gj = tid >> 4;
    const int gc = kwg * 8 + gj;
    const float bI = bias[gc], bF = bias[256 + gc], bG = bias[512 + gc], bO = bias[768 + gc];
    float creg = 0.f;
    __syncthreads();
    const int aoff = n16 * 256 + koff;

    for (int t = 0; t < 100; ++t) {
        if (wave == 0) {   // re-arm slot (t+8)&15 (own-layer lockstep: skew <= 1)
            u32* z = (u32*)(hbufw + ((size_t)((t + 8) & 15)) * 4096)
                   + (lane & 15) * 128 + kwg * 4 + (lane >> 4);
            __hip_atomic_store(z, 0u, __ATOMIC_RELAXED, __HIP_MEMORY_SCOPE_AGENT);
        }
        u32x4 hv[8];
        const u16* hown = hbufw + ((size_t)((t - 1) & 15)) * 4096;
        u32 pend = (t > 0) ? 0xFFu : 0u;
        int guard = 0;
        while (pend) {
#pragma unroll
            for (int kt = 0; kt < 8; ++kt)
                if (pend & (1u << kt)) hv[kt] = ldg16cv4(hown + aoff + kt * 32);
            waitvm();
#pragma unroll
            for (int kt = 0; kt < 8; ++kt)
                if ((pend & (1u << kt)) && hv[kt][0] && hv[kt][1] && hv[kt][2] && hv[kt][3])
                    pend &= ~(1u << kt);
            if (++guard > (1 << 20)) break;
        }
        f32x4 acc[4] = {{0,0,0,0},{0,0,0,0},{0,0,0,0},{0,0,0,0}};
#pragma unroll
        for (int kt = 0; kt < 8; ++kt) {
            short8 a = *(const short8*)(rW + ((size_t)(n16 * 100 + t)) * 256 + koff + kt * 32);
            acc[kt & 3] = mfma16(a, bfr[kt], acc[kt & 3]);
        }
        if (t > 0) {
#pragma unroll
            for (int kt = 0; kt < 8; ++kt) {
                u32x4 d; d[0] = ~hv[kt][0]; d[1] = ~hv[kt][1]; d[2] = ~hv[kt][2]; d[3] = ~hv[kt][3];
                short8 a = __builtin_bit_cast(short8, d);
                acc[kt & 3] = mfma16(a, bfr[8 + kt], acc[kt & 3]);
            }
        }
        const f32x4 C = acc[0] + acc[1] + acc[2] + acc[3];
#pragma unroll
        for (int r = 0; r < 4; ++r) sC[(wave * 16 + quad * 4 + r) * 17 + n16] = C[r];
        __syncthreads();

        const float gi = sC[gb * 17 + gj]            + bI;
        const float gf = sC[gb * 17 + 8 + gj]        + bF;
        const float gg = sC[(16 + gb) * 17 + gj]     + bG;
        const float go = sC[(16 + gb) * 17 + 8 + gj] + bO;
        const float cn = sigm(gf) * creg + sigm(gi) * tanhf(gg);
        const float hn = sigm(go) * tanhf(cn);
        creg = cn;
        hseq[((size_t)(gb * 100 + t)) * 256 + gc] = hn;
        const u32 mb = (u32)f2bf(hn);
        const u32 nb = (u32)__shfl_xor((int)mb, 16, 64);
        if (!(gj & 1)) {
            u32* hd = (u32*)(hbufw + ((size_t)(t & 15)) * 4096) + gb * 128 + kwg * 4 + (gj >> 1);
            __hip_atomic_store(hd, ~(mb | (nb << 16)), __ATOMIC_RELAXED, __HIP_MEMORY_SCOPE_AGENT);
        }
        __syncthreads();   // protect sC reads from next iteration's writes
    }
}

// ---------------------------------------------------------------------------
// Ragged tail-mean pooling from fp32 h3 (in d_out): reps fp32 (ws)
// ---------------------------------------------------------------------------
__global__ void k_pool(const float* __restrict__ h3, const int* __restrict__ x_lens,
                       const int* __restrict__ wstarts, const int* __restrict__ wends,
                       const int* __restrict__ wlens, const int* __restrict__ tailp,
                       float* __restrict__ reps)
{
    const int rw = blockIdx.x;
    const int b = rw / 100, w = rw - b * 100;
    const int tid = threadIdx.x;
    const int xl = x_lens[b];
    const int we = wends[rw];
    const int s0 = wstarts[rw];
    const int wl = wlens[b];
    const int tail = tailp[0];
    int ef = we < xl ? we : xl;
    int sf = s0 > 0 ? s0 : 0;
    int i0 = ef - tail; if (i0 < sf) i0 = sf;
    const bool valid = (w < wl) && (we > 0) && (ef > sf) && (ef > i0);
    float a0 = 0.f, a1 = 0.f;
    if (valid) {
        for (int t = i0; t < ef; ++t) {
            const float* hp = h3 + ((size_t)(b * 2000 + t)) * 512;
            a0 += hp[tid];
            a1 += hp[tid + 256];
        }
        const float inv = 1.f / (float)(ef - i0);
        a0 *= inv; a1 *= inv;
    }
    reps[(size_t)rw * 512 + tid] = a0;
    reps[(size_t)rw * 512 + tid + 256] = a1;
}

// ---------------------------------------------------------------------------
// In-place frame projection: y[b,t,:] = mask(h3[b,t,:]) @ fpW^T + fpb (fp32)
// ---------------------------------------------------------------------------
__global__ __launch_bounds__(256, 2) void k_frame_proj(
    float* __restrict__ y, const int* __restrict__ x_lens,
    const u16* __restrict__ fpWb, const float* __restrict__ fpb)
{
    __shared__ __align__(16) u16 As[16 * 520];
    const int tid = threadIdx.x, lane = tid & 63, wave = tid >> 6;
    const int n16 = lane & 15, quad = lane >> 4, koff = quad * 8;
    const int blk = blockIdx.x;          // 2000 blocks: 125 per batch
    const int b = blk / 125;
    const int t0 = (blk - b * 125) * 16;
    const int xl = x_lens[b];
    for (int c = tid; c < 2048; c += 256) {      // 16 rows x 128 float4
        const int row = c >> 7;
        const int q = c & 127;
        const int t = t0 + row;
        float4 v = {0.f, 0.f, 0.f, 0.f};
        if (t < xl) v = *(const float4*)(y + ((size_t)(b * 2000 + t)) * 512 + q * 4);
        u32* d = (u32*)(As + row * 520 + q * 4);
        d[0] = pk2(v.x, v.y);
        d[1] = pk2(v.z, v.w);
    }
    __syncthreads();
    const size_t rowbase = (size_t)b * 2000 + t0;
    for (int ct = 0; ct < 8; ++ct) {
        const int col0 = (wave * 8 + ct) * 16;
        f32x4 acc = {0, 0, 0, 0};
#pragma unroll
        for (int kt = 0; kt < 16; ++kt) {
            short8 a = *(const short8*)(As + n16 * 520 + kt * 32 + koff);
            short8 wv = *(const short8*)(fpWb + ((size_t)(col0 + n16)) * 512 + kt * 32 + koff);
            acc = mfma16(a, wv, acc);
        }
        const float bn = fpb[col0 + n16];
#pragma unroll
        for (int r = 0; r < 4; ++r) {
            const int m = quad * 4 + r;
            y[(rowbase + m) * 512 + col0 + n16] = acc[r] + bn;
        }
    }
}

// ---------------------------------------------------------------------------
// word_proj: Linear(512->256) + LayerNorm + exact GELU per (b,w) row.
// ---------------------------------------------------------------------------
__global__ void k_word_proj(const float* __restrict__ reps, const float* __restrict__ wpW,
                            const float* __restrict__ wpb, const float* __restrict__ lnW,
                            const float* __restrict__ lnB, u16* __restrict__ rW)
{
    __shared__ float sx[512];
    __shared__ float red[512];
    const int tid = threadIdx.x;
    const int row = blockIdx.x;
    for (int k = tid; k < 512; k += 256) sx[k] = reps[(size_t)row * 512 + k];
    __syncthreads();
    float acc = wpb[tid];
    const float4* wr = (const float4*)(wpW + (size_t)tid * 512);
    for (int k4 = 0; k4 < 128; ++k4) {
        const float4 w = wr[k4];
        acc += sx[k4 * 4] * w.x + sx[k4 * 4 + 1] * w.y + sx[k4 * 4 + 2] * w.z + sx[k4 * 4 + 3] * w.w;
    }
    red[tid] = acc; red[256 + tid] = acc * acc;
    __syncthreads();
    for (int s = 128; s > 0; s >>= 1) {
        if (tid < s) { red[tid] += red[tid + s]; red[256 + tid] += red[256 + tid + s]; }
        __syncthreads();
    }
    const float mu = red[0] * (1.f / 256.f);
    float var = red[256] * (1.f / 256.f) - mu * mu;
    if (var < 0.f) var = 0.f;
    const float xn = (acc - mu) * rsqrtf(var + 1e-5f);
    const float yv = xn * lnW[tid] + lnB[tid];
    const float g = 0.5f * yv * (1.0f + erff(yv * 0.70710678118654752f));
    rW[(size_t)row * 256 + tid] = f2bf(g);
}

// ---------------------------------------------------------------------------
// pred_sem = mask(hseq) @ spW^T + spb  (fp32 vector math)
// ---------------------------------------------------------------------------
__global__ void k_pred(const float* __restrict__ hseq, const int* __restrict__ wlens,
                       const float* __restrict__ spW, const float* __restrict__ spb,
                       float* __restrict__ out)
{
    __shared__ float sh[256];
    const int tid = threadIdx.x;
    const int rw = blockIdx.x;
    const int b = rw / 100, w = rw - b * 100;
    int wl = wlens[b]; if (wl < 1) wl = 1;
    const bool valid = (w < wl);
    sh[tid] = valid ? hseq[(size_t)rw * 256 + tid] : 0.f;
    __syncthreads();
    for (int o = tid; o < 512; o += 256) {
        float acc = spb[o];
        const float4* wr = (const float4*)(spW + (size_t)o * 256);
        for (int k4 = 0; k4 < 64; ++k4) {
            const float4 wv = wr[k4];
            acc += sh[k4 * 4] * wv.x + sh[k4 * 4 + 1] * wv.y + sh[k4 * 4 + 2] * wv.z + sh[k4 * 4 + 3] * wv.w;
        }
        out[PS_OFF + (size_t)rw * 512 + o] = acc;
    }
}

__global__ void k_xlens(const int* __restrict__ x_lens, float* __restrict__ out)
{
    const int tid = threadIdx.x;
    if (tid < 16) out[XL_OFF + tid] = (float)x_lens[tid];
}

// Pre-cast fpW (512x512 fp32) -> bf16
__global__ void k_cvt(const float* __restrict__ src, u16* __restrict__ dst)
{
    const int e = blockIdx.x * 256 + threadIdx.x;   // 65536 float4s
    const float4 v = *(const float4*)(src + (size_t)e * 4);
    u32* d = (u32*)(dst + (size_t)e * 4);
    d[0] = pk2(v.x, v.y);
    d[1] = pk2(v.z, v.w);
}

// Zero flags + frame h ring + word h ring: bytes [0, 950272) = 928x256 u32.
__global__ void k_init(u32* __restrict__ p)
{
    p[blockIdx.x * 256 + threadIdx.x] = 0u;
}

// ---------------------------------------------------------------------------
extern "C" void kernel_launch(void* const* d_in, const int* in_sizes, int n_in,
                              void* d_out, int out_size, void* d_ws, size_t ws_size,
                              hipStream_t stream)
{
    (void)in_sizes; (void)n_in; (void)out_size; (void)ws_size;
    const float* x    = (const float*)d_in[0];
    const int* x_lens = (const int*)d_in[1];
    const int* wstart = (const int*)d_in[2];
    const int* wend   = (const int*)d_in[3];
    const int* wlen   = (const int*)d_in[4];
    const int* tailp  = (const int*)d_in[5];
    const float* Wih0 = (const float*)d_in[6];
    const float* Whh0 = (const float*)d_in[7];
    const float* b0   = (const float*)d_in[8];
    const float* Wih1 = (const float*)d_in[9];
    const float* Whh1 = (const float*)d_in[10];
    const float* b1   = (const float*)d_in[11];
    const float* Wih2 = (const float*)d_in[12];
    const float* Whh2 = (const float*)d_in[13];
    const float* b2   = (const float*)d_in[14];
    const float* fpW  = (const float*)d_in[15];
    const float* fpb  = (const float*)d_in[16];
    const float* wpW  = (const float*)d_in[17];
    const float* wpb  = (const float*)d_in[18];
    const float* lnW  = (const float*)d_in[19];
    const float* lnB  = (const float*)d_in[20];
    const float* wWih = (const float*)d_in[21];
    const float* wWhh = (const float*)d_in[22];
    const float* wb   = (const float*)d_in[23];
    const float* spW  = (const float*)d_in[24];
    const float* spb  = (const float*)d_in[25];

    float* out = (float*)d_out;
    char* ws = (char*)d_ws;
    int* flags  = (int*)(ws + WS_FLAGS);
    u16* hbufF  = (u16*)(ws + WS_HBUF_F);
    u16* hbufW  = (u16*)(ws + WS_HBUF_W);
    float* reps = (float*)(ws + WS_REPS);
    u16* rW     = (u16*)(ws + WS_RW);
    float* hseq = (float*)(ws + WS_HSEQ);
    u16* fpWb   = (u16*)(ws + WS_FPWB);

    k_init<<<928, 256, 0, stream>>>((u32*)d_ws);
    k_cvt<<<256, 256, 0, stream>>>(fpW, fpWb);
    k_frame_lstm<<<192, 128, 0, stream>>>(x, Wih0, Whh0, b0, Wih1, Whh1, b1,
                                          Wih2, Whh2, b2, hbufF, flags, out);
    k_pool<<<1600, 256, 0, stream>>>(out, x_lens, wstart, wend, wlen, tailp, reps);
    k_frame_proj<<<2000, 256, 0, stream>>>(out, x_lens, fpWb, fpb);  // after k_pool (in-place)
    k_word_proj<<<1600, 256, 0, stream>>>(reps, wpW, wpb, lnW, lnB, rW);
    k_word_lstm<<<32, 128, 0, stream>>>(rW, wWih, wWhh, wb, hbufW, hseq);
    k_pred<<<1600, 256, 0, stream>>>(hseq, wlen, spW, spb, out);
    k_xlens<<<1, 64, 0, stream>>>(x_lens, out);
}

// Round 2
// 8174.863 us; speedup vs baseline: 1.3794x; 1.3794x over previous
//
#include <hip/hip_runtime.h>
#include <math.h>

typedef unsigned short u16;
typedef unsigned int   u32;
typedef unsigned long long u64;
typedef __attribute__((ext_vector_type(8))) short short8;
typedef __attribute__((ext_vector_type(4))) float f32x4;

__device__ __forceinline__ float bf2f(u16 v) { return __uint_as_float(((u32)v) << 16); }
__device__ __forceinline__ u16 f2bf(float f) {
    u32 u = __float_as_uint(f);
    u32 r = (u + 0x7fffu + ((u >> 16) & 1u)) >> 16;
    return (u16)r;
}
__device__ __forceinline__ u32 pk2(float a, float b) {
    return ((u32)f2bf(a)) | (((u32)f2bf(b)) << 16);
}
__device__ __forceinline__ float sigm(float x) { return 1.f / (1.f + __expf(-x)); }
__device__ __forceinline__ f32x4 mfma16(short8 a, short8 b, f32x4 c) {
    return __builtin_amdgcn_mfma_f32_16x16x32_bf16(a, b, c, 0, 0, 0);
}
__device__ __forceinline__ short8 ld8bf(const float* p) {
    short8 r;
#pragma unroll
    for (int j = 0; j < 8; ++j) r[j] = (short)f2bf(p[j]);
    return r;
}
// 16B cache-bypassing load straight to/from the coherence point.
__device__ __forceinline__ short8 ldg16cv(const u16* p) {
    short8 r;
    asm volatile("global_load_dwordx4 %0, %1, off sc0 sc1" : "=v"(r) : "v"(p));
    return r;
}
__device__ __forceinline__ void waitvm() {
    asm volatile("s_waitcnt vmcnt(0)" ::: "memory");
}

#define FLAG_STRIDE 16   /* ints -> 64B per flag slot */
#define NPAR 8           /* h ring depth */
#define BIGF (1 << 26)
#define XL_OFF 16384000
#define PS_OFF 16384016

// ws layout (bytes) -- identical to the proven round-0 layout
#define WS_FLAGS   0        /* flag slots x 64B, padded to 32768 */
#define WS_HBUF_F  32768    /* 3 layers x 8 slots x 16KB = 393216 */
#define WS_HBUF_W  425984   /* 8 slots x 8KB = 65536 */
#define WS_REPS    491520   /* 1600x512 fp32 = 3276800 */
#define WS_RW      3768320  /* 1600x256 bf16 = 819200 */
#define WS_HSEQ    4587520  /* 1600x256 fp32 = 1638400 */
#define WS_FPWB    6225920  /* 512x512 bf16 = 524288 -> end 6750208 */

// ---------------------------------------------------------------------------
// Persistent 3-layer frame LSTM. 48 WGs (16 per layer), 512 threads each.
// WG owns 32 h-cols (128 gate rows); 8 waves = 2 gate-pairs x 4 col-subgroups.
// Flag protocol identical to the proven scheme: producers store h (bf16 pairs),
// per-wave waitvm ack + barrier, then one flag store; consumers poll 3x16
// flags (prev layer, own peers, ring anti-dep) then fetch guaranteed-valid h.
// Consolidation (64->16 WGs/layer) shrinks the per-step straggler max and the
// synchronized L3 burst while keeping per-wave MFMA work and VGPRs identical.
// ---------------------------------------------------------------------------
template<int KTIN, bool L0>
__device__ __forceinline__ void frame_body(
    const int layer, const int kwg,
    const float* __restrict__ Wih, const float* __restrict__ Whh, const float* __restrict__ bias,
    const float* __restrict__ x, u16* __restrict__ hbuf, int* __restrict__ flags,
    float* __restrict__ h3out, float* sC, u16* sxpad, u16* AsIn, u16* AsOwn)
{
    const int tid  = threadIdx.x;
    const int lane = tid & 63;
    const int wave = tid >> 6;      // 0..7
    const int n16  = lane & 15;
    const int quad = lane >> 4;
    const int koff = quad * 8;
    const int gp   = wave >> 2;     // 0: (i|f) tile, 1: (g|o) tile
    const int cs   = wave & 3;      // col-subgroup of 8 cols

    if (L0) {                       // zero the x pad cols [80,96)
        if (tid < 256) sxpad[(tid >> 4) * 96 + 80 + (tid & 15)] = 0;
    }

    // B fragments in registers: 16 gate rows per wave, K = KTIN*32 (in) + 512 (own)
    const int grow = gp * 1024 + ((n16 >> 3) * 512) + kwg * 32 + cs * 8 + (n16 & 7);
    short8 bfr[KTIN + 16];
#pragma unroll
    for (int kt = 0; kt < KTIN; ++kt) {
        short8 v = {0,0,0,0,0,0,0,0};
        const int k = kt * 32 + koff;
        if (L0) { if (k + 8 <= 80) v = ld8bf(Wih + grow * 80 + k); }
        else    { v = ld8bf(Wih + (size_t)grow * 512 + k); }
        bfr[kt] = v;
    }
#pragma unroll
    for (int kt = 0; kt < 16; ++kt)
        bfr[KTIN + kt] = ld8bf(Whh + (size_t)grow * 512 + kt * 32 + koff);

    // gate phase: one (batch, col) value per thread; c-state in a register
    const int gb = tid & 15;        // batch
    const int gj = tid >> 4;        // col within WG, 0..31
    const int gc = kwg * 32 + gj;   // global h col
    const float bI = bias[gc], bF = bias[512 + gc], bG = bias[1024 + gc], bO = bias[1536 + gc];
    float creg = 0.f;

    // flag groups of 16: g0=dummy-prev(BIGF), g1..3 = L0..L2, g4=dummy-next(BIGF)
    const int* fP = flags + (layer * 16) * FLAG_STRIDE;
    const int* fO = flags + ((layer + 1) * 16) * FLAG_STRIDE;
    const int* fN = flags + ((layer + 2) * 16) * FLAG_STRIDE;
    int* myflag   = flags + ((layer + 1) * 16 + kwg) * FLAG_STRIDE;
    const u16* pbase = hbuf + (size_t)((layer > 0 ? layer - 1 : 0) * NPAR) * 8192;
    u16* lbase = hbuf + (size_t)(layer * NPAR) * 8192;
    __syncthreads();

    for (int t = 0; t < 2000; ++t) {
        // ---- wait for producers / own peers / ring anti-dependency ----
        if (wave == 0) {
            const int idx = lane & 15;
            int guard = 0;
            for (;;) {
                const int fp = __hip_atomic_load(fP + idx * FLAG_STRIDE, __ATOMIC_RELAXED, __HIP_MEMORY_SCOPE_AGENT);
                const int fo = __hip_atomic_load(fO + idx * FLAG_STRIDE, __ATOMIC_RELAXED, __HIP_MEMORY_SCOPE_AGENT);
                const int fn = __hip_atomic_load(fN + idx * FLAG_STRIDE, __ATOMIC_RELAXED, __HIP_MEMORY_SCOPE_AGENT);
                if (__all((fp >= t + 1) && (fo >= t) && (fn >= t - 7))) break;
                if (++guard > (1 << 22)) break;   // anti-hang escape
                __builtin_amdgcn_s_sleep(1);
            }
        }
        __syncthreads();

        // ---- stage h (and x) into LDS: 2 chunks of 16B per thread ----
        const u16* hin  = pbase + ((size_t)(t & 7)) * 8192;
        const u16* hown = lbase + ((size_t)((t + 7) & 7)) * 8192;
        const int c0 = tid, c1 = tid + 512;
        short8 rin0, rin1, rown0, rown1;
        float4 xv;
        if (L0) {
            if (tid < 320)
                xv = *(const float4*)(x + ((size_t)(tid / 20) * 2000 + t) * 80 + (tid % 20) * 4);
        } else {
            rin0 = ldg16cv(hin + c0 * 8);
            rin1 = ldg16cv(hin + c1 * 8);
        }
        rown0 = ldg16cv(hown + c0 * 8);
        rown1 = ldg16cv(hown + c1 * 8);
        waitvm();
        if (L0) {
            if (tid < 320) {
                u32* d = (u32*)(sxpad + (tid / 20) * 96 + (tid % 20) * 4);
                d[0] = pk2(xv.x, xv.y); d[1] = pk2(xv.z, xv.w);
            }
        } else {
            *(short8*)(AsIn + (c0 >> 6) * 520 + ((c0 & 63) << 3)) = rin0;
            *(short8*)(AsIn + (c1 >> 6) * 520 + ((c1 & 63) << 3)) = rin1;
        }
        *(short8*)(AsOwn + (c0 >> 6) * 520 + ((c0 & 63) << 3)) = rown0;
        *(short8*)(AsOwn + (c1 >> 6) * 520 + ((c1 & 63) << 3)) = rown1;
        __syncthreads();

        // ---- gate GEMM ----
        f32x4 acc[4] = {{0,0,0,0},{0,0,0,0},{0,0,0,0},{0,0,0,0}};
#pragma unroll
        for (int kt = 0; kt < KTIN; ++kt) {
            short8 a;
            if (L0) a = *(const short8*)(sxpad + n16 * 96 + kt * 32 + koff);
            else    a = *(const short8*)(AsIn + n16 * 520 + kt * 32 + koff);
            acc[kt & 3] = mfma16(a, bfr[kt], acc[kt & 3]);
        }
#pragma unroll
        for (int kt = 0; kt < 16; ++kt) {
            short8 a = *(const short8*)(AsOwn + n16 * 520 + kt * 32 + koff);
            acc[(KTIN + kt) & 3] = mfma16(a, bfr[KTIN + kt], acc[(KTIN + kt) & 3]);
        }
        const f32x4 C = acc[0] + acc[1] + acc[2] + acc[3];
#pragma unroll
        for (int r = 0; r < 4; ++r)
            sC[(gp * 16 + quad * 4 + r) * 65 + cs * 16 + n16] = C[r];
        __syncthreads();

        // ---- gate math on all 512 lanes + publish ----
        const int cs2 = gj >> 3, jl = gj & 7;
        const float gi = sC[gb * 65 + cs2 * 16 + jl]            + bI;
        const float gf = sC[gb * 65 + cs2 * 16 + 8 + jl]        + bF;
        const float gg = sC[(16 + gb) * 65 + cs2 * 16 + jl]     + bG;
        const float go = sC[(16 + gb) * 65 + cs2 * 16 + 8 + jl] + bO;
        const float cn = sigm(gf) * creg + sigm(gi) * tanhf(gg);
        const float hn = sigm(go) * tanhf(cn);
        creg = cn;
        if (layer == 2)
            h3out[((size_t)(gb * 2000 + t)) * 512 + gc] = hn;
        const u32 mb = (u32)f2bf(hn);
        const u32 nb = (u32)__shfl_xor((int)mb, 16, 64);
        if (!(gj & 1)) {
            u32* hd = (u32*)(lbase + ((size_t)(t & 7)) * 8192) + gb * 256 + kwg * 16 + (gj >> 1);
            __hip_atomic_store(hd, mb | (nb << 16), __ATOMIC_RELAXED, __HIP_MEMORY_SCOPE_AGENT);
        }
        waitvm();           // each wave drains its own publish stores
        __syncthreads();    // all publishers acked before the flag
        if (tid == 0)
            __hip_atomic_store(myflag, t + 1, __ATOMIC_RELAXED, __HIP_MEMORY_SCOPE_AGENT);
    }
}

__global__ __launch_bounds__(512, 1) void k_frame_lstm(
    const float* __restrict__ x,
    const float* __restrict__ Wih0, const float* __restrict__ Whh0, const float* __restrict__ b0,
    const float* __restrict__ Wih1, const float* __restrict__ Whh1, const float* __restrict__ b1,
    const float* __restrict__ Wih2, const float* __restrict__ Whh2, const float* __restrict__ b2,
    u16* hbuf, int* flags, float* h3out)
{
    __shared__ __align__(16) u16 sxpad[16 * 96];
    __shared__ __align__(16) u16 AsIn[16 * 520];
    __shared__ __align__(16) u16 AsOwn[16 * 520];
    __shared__ float sC[32 * 65];
    const int wgid = blockIdx.x;
    const int layer = wgid >> 4;
    const int kwg = wgid & 15;
    if (layer == 0)      frame_body<3,  true >(0, kwg, Wih0, Whh0, b0, x, hbuf, flags, h3out, sC, sxpad, AsIn, AsOwn);
    else if (layer == 1) frame_body<16, false>(1, kwg, Wih1, Whh1, b1, x, hbuf, flags, h3out, sC, sxpad, AsIn, AsOwn);
    else                 frame_body<16, false>(2, kwg, Wih2, Whh2, b2, x, hbuf, flags, h3out, sC, sxpad, AsIn, AsOwn);
}

// ---------------------------------------------------------------------------
// Persistent word LSTM: 8 WGs x 512 threads, 100 steps, H=256, K=256+256.
// Same flag scheme (own-layer only, group base slot 80), ring-8 h buffer.
// A-operands (rW row-slice + own h) LDS-deduped: 1 chunk per thread each.
// ---------------------------------------------------------------------------
__global__ __launch_bounds__(512, 1) void k_word_lstm(
    const u16* __restrict__ rW, const float* __restrict__ Wih,
    const float* __restrict__ Whh, const float* __restrict__ bias,
    u16* __restrict__ hbufw, int* __restrict__ flags, float* __restrict__ hseq)
{
    __shared__ __align__(16) u16 AsIn[16 * 264];
    __shared__ __align__(16) u16 AsOwn[16 * 264];
    __shared__ float sC[32 * 65];
    const int tid = threadIdx.x;
    const int lane = tid & 63;
    const int wave = tid >> 6;
    const int n16 = lane & 15;
    const int quad = lane >> 4;
    const int koff = quad * 8;
    const int gp = wave >> 2;
    const int cs = wave & 3;
    const int kwg = blockIdx.x;  // 0..7

    const int grow = gp * 512 + ((n16 >> 3) * 256) + kwg * 32 + cs * 8 + (n16 & 7);
    short8 bfr[16];
#pragma unroll
    for (int kt = 0; kt < 8; ++kt) bfr[kt]     = ld8bf(Wih + (size_t)grow * 256 + kt * 32 + koff);
#pragma unroll
    for (int kt = 0; kt < 8; ++kt) bfr[8 + kt] = ld8bf(Whh + (size_t)grow * 256 + kt * 32 + koff);
    const int gb = tid & 15;
    const int gj = tid >> 4;        // 0..31
    const int gc = kwg * 32 + gj;
    const float bI = bias[gc], bF = bias[256 + gc], bG = bias[512 + gc], bO = bias[768 + gc];
    float creg = 0.f;
    const int* fO = flags + 80 * FLAG_STRIDE;
    int* myflag   = flags + (80 + kwg) * FLAG_STRIDE;
    __syncthreads();

    for (int t = 0; t < 100; ++t) {
        if (wave == 0) {
            const int idx = lane & 7;
            int guard = 0;
            for (;;) {
                const int fo = __hip_atomic_load(fO + idx * FLAG_STRIDE, __ATOMIC_RELAXED, __HIP_MEMORY_SCOPE_AGENT);
                if (__all(fo >= t)) break;
                if (++guard > (1 << 22)) break;
                __builtin_amdgcn_s_sleep(1);
            }
        }
        __syncthreads();

        // stage rW row-slice (cached load) + own h (bypass): 1 chunk each
        const u16* hown = hbufw + ((size_t)((t + 7) & 7)) * 4096;
        const int b = tid >> 5, k8 = (tid & 31) << 3;
        const short8 rv = *(const short8*)(rW + ((size_t)(b * 100 + t)) * 256 + k8);
        const short8 hv = ldg16cv(hown + tid * 8);
        waitvm();
        *(short8*)(AsIn + b * 264 + k8) = rv;
        *(short8*)(AsOwn + b * 264 + k8) = hv;
        __syncthreads();

        f32x4 acc[4] = {{0,0,0,0},{0,0,0,0},{0,0,0,0},{0,0,0,0}};
#pragma unroll
        for (int kt = 0; kt < 8; ++kt) {
            short8 a = *(const short8*)(AsIn + n16 * 264 + kt * 32 + koff);
            acc[kt & 3] = mfma16(a, bfr[kt], acc[kt & 3]);
        }
#pragma unroll
        for (int kt = 0; kt < 8; ++kt) {
            short8 a = *(const short8*)(AsOwn + n16 * 264 + kt * 32 + koff);
            acc[kt & 3] = mfma16(a, bfr[8 + kt], acc[kt & 3]);
        }
        const f32x4 C = acc[0] + acc[1] + acc[2] + acc[3];
#pragma unroll
        for (int r = 0; r < 4; ++r)
            sC[(gp * 16 + quad * 4 + r) * 65 + cs * 16 + n16] = C[r];
        __syncthreads();

        const int cs2 = gj >> 3, jl = gj & 7;
        const float gi = sC[gb * 65 + cs2 * 16 + jl]            + bI;
        const float gf = sC[gb * 65 + cs2 * 16 + 8 + jl]        + bF;
        const float gg = sC[(16 + gb) * 65 + cs2 * 16 + jl]     + bG;
        const float go = sC[(16 + gb) * 65 + cs2 * 16 + 8 + jl] + bO;
        const float cn = sigm(gf) * creg + sigm(gi) * tanhf(gg);
        const float hn = sigm(go) * tanhf(cn);
        creg = cn;
        hseq[((size_t)(gb * 100 + t)) * 256 + gc] = hn;
        const u32 mb = (u32)f2bf(hn);
        const u32 nb = (u32)__shfl_xor((int)mb, 16, 64);
        if (!(gj & 1)) {
            u32* hd = (u32*)(hbufw + ((size_t)(t & 7)) * 4096) + gb * 128 + kwg * 16 + (gj >> 1);
            __hip_atomic_store(hd, mb | (nb << 16), __ATOMIC_RELAXED, __HIP_MEMORY_SCOPE_AGENT);
        }
        waitvm();
        __syncthreads();
        if (tid == 0)
            __hip_atomic_store(myflag, t + 1, __ATOMIC_RELAXED, __HIP_MEMORY_SCOPE_AGENT);
    }
}

// ---------------------------------------------------------------------------
// Ragged tail-mean pooling from fp32 h3 (in d_out): reps fp32 (ws)
// ---------------------------------------------------------------------------
__global__ void k_pool(const float* __restrict__ h3, const int* __restrict__ x_lens,
                       const int* __restrict__ wstarts, const int* __restrict__ wends,
                       const int* __restrict__ wlens, const int* __restrict__ tailp,
                       float* __restrict__ reps)
{
    const int rw = blockIdx.x;
    const int b = rw / 100, w = rw - b * 100;
    const int tid = threadIdx.x;
    const int xl = x_lens[b];
    const int we = wends[rw];
    const int s0 = wstarts[rw];
    const int wl = wlens[b];
    const int tail = tailp[0];
    int ef = we < xl ? we : xl;
    int sf = s0 > 0 ? s0 : 0;
    int i0 = ef - tail; if (i0 < sf) i0 = sf;
    const bool valid = (w < wl) && (we > 0) && (ef > sf) && (ef > i0);
    float a0 = 0.f, a1 = 0.f;
    if (valid) {
        for (int t = i0; t < ef; ++t) {
            const float* hp = h3 + ((size_t)(b * 2000 + t)) * 512;
            a0 += hp[tid];
            a1 += hp[tid + 256];
        }
        const float inv = 1.f / (float)(ef - i0);
        a0 *= inv; a1 *= inv;
    }
    reps[(size_t)rw * 512 + tid] = a0;
    reps[(size_t)rw * 512 + tid + 256] = a1;
}

// ---------------------------------------------------------------------------
// In-place frame projection: y[b,t,:] = mask(h3[b,t,:]) @ fpW^T + fpb (fp32)
// ---------------------------------------------------------------------------
__global__ __launch_bounds__(256, 2) void k_frame_proj(
    float* __restrict__ y, const int* __restrict__ x_lens,
    const u16* __restrict__ fpWb, const float* __restrict__ fpb)
{
    __shared__ __align__(16) u16 As[16 * 520];
    const int tid = threadIdx.x, lane = tid & 63, wave = tid >> 6;
    const int n16 = lane & 15, quad = lane >> 4, koff = quad * 8;
    const int blk = blockIdx.x;          // 2000 blocks: 125 per batch
    const int b = blk / 125;
    const int t0 = (blk - b * 125) * 16;
    const int xl = x_lens[b];
    for (int c = tid; c < 2048; c += 256) {      // 16 rows x 128 float4
        const int row = c >> 7;
        const int q = c & 127;
        const int t = t0 + row;
        float4 v = {0.f, 0.f, 0.f, 0.f};
        if (t < xl) v = *(const float4*)(y + ((size_t)(b * 2000 + t)) * 512 + q * 4);
        u32* d = (u32*)(As + row * 520 + q * 4);
        d[0] = pk2(v.x, v.y);
        d[1] = pk2(v.z, v.w);
    }
    __syncthreads();
    const size_t rowbase = (size_t)b * 2000 + t0;
    for (int ct = 0; ct < 8; ++ct) {
        const int col0 = (wave * 8 + ct) * 16;
        f32x4 acc = {0, 0, 0, 0};
#pragma unroll
        for (int kt = 0; kt < 16; ++kt) {
            short8 a = *(const short8*)(As + n16 * 520 + kt * 32 + koff);
            short8 wv = *(const short8*)(fpWb + ((size_t)(col0 + n16)) * 512 + kt * 32 + koff);
            acc = mfma16(a, wv, acc);
        }
        const float bn = fpb[col0 + n16];
#pragma unroll
        for (int r = 0; r < 4; ++r) {
            const int m = quad * 4 + r;
            y[(rowbase + m) * 512 + col0 + n16] = acc[r] + bn;
        }
    }
}

// ---------------------------------------------------------------------------
// word_proj: Linear(512->256) + LayerNorm + exact GELU per (b,w) row.
// ---------------------------------------------------------------------------
__global__ void k_word_proj(const float* __restrict__ reps, const float* __restrict__ wpW,
                            const float* __restrict__ wpb, const float* __restrict__ lnW,
                            const float* __restrict__ lnB, u16* __restrict__ rW)
{
    __shared__ float sx[512];
    __shared__ float red[512];
    const int tid = threadIdx.x;
    const int row = blockIdx.x;
    for (int k = tid; k < 512; k += 256) sx[k] = reps[(size_t)row * 512 + k];
    __syncthreads();
    float acc = wpb[tid];
    const float4* wr = (const float4*)(wpW + (size_t)tid * 512);
    for (int k4 = 0; k4 < 128; ++k4) {
        const float4 w = wr[k4];
        acc += sx[k4 * 4] * w.x + sx[k4 * 4 + 1] * w.y + sx[k4 * 4 + 2] * w.z + sx[k4 * 4 + 3] * w.w;
    }
    red[tid] = acc; red[256 + tid] = acc * acc;
    __syncthreads();
    for (int s = 128; s > 0; s >>= 1) {
        if (tid < s) { red[tid] += red[tid + s]; red[256 + tid] += red[256 + tid + s]; }
        __syncthreads();
    }
    const float mu = red[0] * (1.f / 256.f);
    float var = red[256] * (1.f / 256.f) - mu * mu;
    if (var < 0.f) var = 0.f;
    const float xn = (acc - mu) * rsqrtf(var + 1e-5f);
    const float yv = xn * lnW[tid] + lnB[tid];
    const float g = 0.5f * yv * (1.0f + erff(yv * 0.70710678118654752f));
    rW[(size_t)row * 256 + tid] = f2bf(g);
}

// ---------------------------------------------------------------------------
// pred_sem = mask(hseq) @ spW^T + spb  (fp32 vector math)
// ---------------------------------------------------------------------------
__global__ void k_pred(const float* __restrict__ hseq, const int* __restrict__ wlens,
                       const float* __restrict__ spW, const float* __restrict__ spb,
                       float* __restrict__ out)
{
    __shared__ float sh[256];
    const int tid = threadIdx.x;
    const int rw = blockIdx.x;
    const int b = rw / 100, w = rw - b * 100;
    int wl = wlens[b]; if (wl < 1) wl = 1;
    const bool valid = (w < wl);
    sh[tid] = valid ? hseq[(size_t)rw * 256 + tid] : 0.f;
    __syncthreads();
    for (int o = tid; o < 512; o += 256) {
        float acc = spb[o];
        const float4* wr = (const float4*)(spW + (size_t)o * 256);
        for (int k4 = 0; k4 < 64; ++k4) {
            const float4 wv = wr[k4];
            acc += sh[k4 * 4] * wv.x + sh[k4 * 4 + 1] * wv.y + sh[k4 * 4 + 2] * wv.z + sh[k4 * 4 + 3] * wv.w;
        }
        out[PS_OFF + (size_t)rw * 512 + o] = acc;
    }
}

__global__ void k_xlens(const int* __restrict__ x_lens, float* __restrict__ out)
{
    const int tid = threadIdx.x;
    if (tid < 16) out[XL_OFF + tid] = (float)x_lens[tid];
}

// Pre-cast fpW (512x512 fp32) -> bf16
__global__ void k_cvt(const float* __restrict__ src, u16* __restrict__ dst)
{
    const int e = blockIdx.x * 256 + threadIdx.x;   // 65536 float4s
    const float4 v = *(const float4*)(src + (size_t)e * 4);
    u32* d = (u32*)(dst + (size_t)e * 4);
    d[0] = pk2(v.x, v.y);
    d[1] = pk2(v.z, v.w);
}

// Init flags (BIGF sentinels for dummy prev/next groups) + zero h rings.
// Covers bytes [0, 491520): 480 blocks x 256 threads x 1 u32.
// Flag groups of 16 slots: g0 = dummy-prev (BIGF), g1..g3 = frame L0..L2,
// g4 = dummy-next (BIGF), slots [80,88) = word LSTM.
__global__ void k_init(u32* __restrict__ p)
{
    const int idx = blockIdx.x * 256 + threadIdx.x;
    u32 v = 0u;
    if (idx < 8192) {                      // flag area (32 KB)
        const int slot = idx >> 4;
        if (slot < 16 || (slot >= 64 && slot < 80)) v = (u32)BIGF;
    }
    p[idx] = v;
}

// ---------------------------------------------------------------------------
extern "C" void kernel_launch(void* const* d_in, const int* in_sizes, int n_in,
                              void* d_out, int out_size, void* d_ws, size_t ws_size,
                              hipStream_t stream)
{
    (void)in_sizes; (void)n_in; (void)out_size; (void)ws_size;
    const float* x    = (const float*)d_in[0];
    const int* x_lens = (const int*)d_in[1];
    const int* wstart = (const int*)d_in[2];
    const int* wend   = (const int*)d_in[3];
    const int* wlen   = (const int*)d_in[4];
    const int* tailp  = (const int*)d_in[5];
    const float* Wih0 = (const float*)d_in[6];
    const float* Whh0 = (const float*)d_in[7];
    const float* b0   = (const float*)d_in[8];
    const float* Wih1 = (const float*)d_in[9];
    const float* Whh1 = (const float*)d_in[10];
    const float* b1   = (const float*)d_in[11];
    const float* Wih2 = (const float*)d_in[12];
    const float* Whh2 = (const float*)d_in[13];
    const float* b2   = (const float*)d_in[14];
    const float* fpW  = (const float*)d_in[15];
    const float* fpb  = (const float*)d_in[16];
    const float* wpW  = (const float*)d_in[17];
    const float* wpb  = (const float*)d_in[18];
    const float* lnW  = (const float*)d_in[19];
    const float* lnB  = (const float*)d_in[20];
    const float* wWih = (const float*)d_in[21];
    const float* wWhh = (const float*)d_in[22];
    const float* wb   = (const float*)d_in[23];
    const float* spW  = (const float*)d_in[24];
    const float* spb  = (const float*)d_in[25];

    float* out = (float*)d_out;
    char* ws = (char*)d_ws;
    int* flags  = (int*)(ws + WS_FLAGS);
    u16* hbufF  = (u16*)(ws + WS_HBUF_F);
    u16* hbufW  = (u16*)(ws + WS_HBUF_W);
    float* reps = (float*)(ws + WS_REPS);
    u16* rW     = (u16*)(ws + WS_RW);
    float* hseq = (float*)(ws + WS_HSEQ);
    u16* fpWb   = (u16*)(ws + WS_FPWB);

    k_init<<<480, 256, 0, stream>>>((u32*)d_ws);
    k_cvt<<<256, 256, 0, stream>>>(fpW, fpWb);
    k_frame_lstm<<<48, 512, 0, stream>>>(x, Wih0, Whh0, b0, Wih1, Whh1, b1,
                                         Wih2, Whh2, b2, hbufF, flags, out);
    k_pool<<<1600, 256, 0, stream>>>(out, x_lens, wstart, wend, wlen, tailp, reps);
    k_frame_proj<<<2000, 256, 0, stream>>>(out, x_lens, fpWb, fpb);  // after k_pool (in-place)
    k_word_proj<<<1600, 256, 0, stream>>>(reps, wpW, wpb, lnW, lnB, rW);
    k_word_lstm<<<8, 512, 0, stream>>>(rW, wWih, wWhh, wb, hbufW, flags, hseq);
    k_pred<<<1600, 256, 0, stream>>>(hseq, wlen, spW, spb, out);
    k_xlens<<<1, 64, 0, stream>>>(x_lens, out);
}